// Round 1
// baseline (325.878 us; speedup 1.0000x reference)
//
#include <hip/hip_runtime.h>

// Dequantize: out[g*4..g*4+3] = codebook[cb(g)][codes[g]] * scales[g/16]
//   N_GROUPS = 16,777,216 (8192*8192/4); first half uses codebook 0, second half codebook 1.
//   Codebook: 2 x 256 x float4 (8 KB, 4 KB per half) -> staged in LDS per block.
//
// Block covers 2048 consecutive groups (256 thr x 8 groups/thr, stride-256
// interleave so every load/store instruction is a contiguous wave access).
// HALF (8,388,608) is a multiple of 2048, so the codebook half is block-uniform.
//
// R1 change vs previous best: output stores are REGULAR stores (not
// __builtin_nontemporal_store). Theory: nt stores bypass L2 write-combining
// and cap the 268 MB write stream ~3x below the 6.5 TB/s the harness's own
// fillBuffer sustains with plain stores on the same buffer. scales load is
// also un-nt'd (each 64B scale line is reused 4x within a block). codes keep
// nt (read-once stream, each fetched segment fully consumed by one wave instr).

#define N_GROUPS  16777216
#define HALF      8388608
#define GPT       8
#define BLOCK     256
#define GROUPS_PER_BLOCK (BLOCK * GPT)   // 2048

typedef float f32x4 __attribute__((ext_vector_type(4)));

__global__ __launch_bounds__(256) void dequant_kernel(
    const f32x4* __restrict__ codebooks,  // [2*256] float4
    const float* __restrict__ scales,     // [N_GROUPS/16]
    const int*   __restrict__ codes,      // [N_GROUPS]
    f32x4*       __restrict__ out)        // [N_GROUPS]
{
    __shared__ f32x4 lut[256];

    const int base = blockIdx.x * GROUPS_PER_BLOCK;
    const int half = (base >= HALF) ? 256 : 0;   // block-uniform (scalar)

    // Stage this block's codebook half: 256 lanes x 16 B = 4 KB, one instruction.
    lut[threadIdx.x] = codebooks[half + threadIdx.x];
    __syncthreads();

    int   code[GPT];
    float s[GPT];

    // Batch the streaming loads first: 8 independent chains in flight.
    #pragma unroll
    for (int k = 0; k < GPT; ++k) {
        const int g = base + k * BLOCK + threadIdx.x;
        code[k] = __builtin_nontemporal_load(&codes[g]);   // read-once stream
        s[k]    = scales[g >> 4];                          // cached: 4x reuse per line in-block
    }

    #pragma unroll
    for (int k = 0; k < GPT; ++k) {
        const int g = base + k * BLOCK + threadIdx.x;
        f32x4 c = lut[code[k]];                            // ds_read_b128 gather
        c *= s[k];
        out[g] = c;                                        // regular store: L2 write-combine
    }
}

extern "C" void kernel_launch(void* const* d_in, const int* in_sizes, int n_in,
                              void* d_out, int out_size, void* d_ws, size_t ws_size,
                              hipStream_t stream) {
    const f32x4* codebooks = (const f32x4*)d_in[0];
    const float* scales    = (const float*)d_in[1];
    const int*   codes     = (const int*)d_in[2];
    f32x4*       out       = (f32x4*)d_out;

    dequant_kernel<<<N_GROUPS / GROUPS_PER_BLOCK, BLOCK, 0, stream>>>(
        codebooks, scales, codes, out);
}